// Round 2
// baseline (1244.083 us; speedup 1.0000x reference)
//
#include <hip/hip_runtime.h>

// DA-RNN forward, fully fused: one block per batch element (B=512).
// Dims: T=64 steps, 63 input series, H=D=E=128, gates 4H=512 = blockDim.
// Thread j owns row j of the recurrent weight matrices in registers.
// R2: __launch_bounds__(512,1) -> 256-VGPR cap (no spill); 4-acc ILP in dot
// products; bank-conflict-free rotated chunk order in dec P1/P2.

__device__ __forceinline__ float fast_rcp(float x) {
    return __builtin_amdgcn_rcpf(x);
}
__device__ __forceinline__ float fast_tanh(float x) {
    // tanh(x) = 1 - 2/(1+e^{2x}); safe at +-inf
    return 1.f - 2.f * fast_rcp(1.f + __expf(2.f * x));
}
__device__ __forceinline__ float fast_sig(float x) {
    return fast_rcp(1.f + __expf(-x));
}

__global__ __launch_bounds__(512, 1) void darnn_fused(
    const float* __restrict__ x,                                    // (512,64,64)
    const float* __restrict__ aW,  const float* __restrict__ ab,    // (320),(1)
    const float* __restrict__ eWih, const float* __restrict__ eWhh, // (512,63),(512,128)
    const float* __restrict__ ebih, const float* __restrict__ ebhh, // (512),(512)
    const float* __restrict__ dW1,  const float* __restrict__ db1,  // (128,384),(128)
    const float* __restrict__ W2,                                   // (128)  [dec_W2 row 0]
    const float* __restrict__ dWih, const float* __restrict__ dWhh, // (512,1),(512,128)
    const float* __restrict__ dbih, const float* __restrict__ dbhh, // (512),(512)
    const float* __restrict__ fcW,  const float* __restrict__ fcb,  // (129),(1)
    const float* __restrict__ fcfW, const float* __restrict__ fcfb, // (256),(1)
    float* __restrict__ out)                                        // (512)
{
    const int b   = blockIdx.x;
    const int tid = threadIdx.x;
    const float* xb = x + b * 4096;   // x[b,t,s] = xb[t*64+s]

    __shared__ float s_enc[64 * 128]; // input_encoded[t][e]   32KB
    __shared__ float s_ep [64 * 128]; // enc_proj[t][f] (+b1)  32KB
    __shared__ float s_attn[64];      // encoder input attention (time-invariant!)
    __shared__ float s_wi[64];        // attn * x_t  (padded, [63]=0)
    __shared__ float s_g[512];        // activated gates
    __shared__ float s_hc[256];       // [h(128); c(128)]
    __shared__ float s_hp[128];       // h@W1h.T + c@W1c.T
    __shared__ float s_sc[64];        // dec scores -> attn
    __shared__ float s_cp[512];       // context partials
    __shared__ float s_ctx[128];      // context
    __shared__ float s_W2v[128];
    __shared__ float s_fc[130];       // fc_W(129) + fc_b
    __shared__ float s_yt;

    if (tid < 128) s_W2v[tid] = W2[tid];
    if (tid < 130) s_fc[tid] = (tid < 129) ? fcW[tid] : fcb[0];

    // ================= encoder =================
    {
        // per-thread weights: row `tid` of enc_Wih (63, padded) and enc_Whh (128)
        float wih[64];
        float whh[128];
#pragma unroll
        for (int n = 0; n < 63; ++n) wih[n] = eWih[tid * 63 + n];
        wih[63] = 0.f;
#pragma unroll
        for (int k = 0; k < 128; ++k) whh[k] = eWhh[tid * 128 + k];
        const float bias = ebih[tid] + ebhh[tid];

        // prologue: encoder input attention. score = h@Wh + c@Wc is a per-row
        // SCALAR broadcast over series -> softmax is shift-invariant -> attn is
        // constant over time: attn = softmax_n( sum_t x[b,t,n+1]*Wt[t] + ab ).
        if (tid < 64) {
            float sc = -1e30f;
            if (tid < 63) {
                sc = ab[0];
                for (int t = 0; t < 64; ++t) sc += xb[t * 64 + tid + 1] * aW[256 + t];
            }
            float m = sc;
#pragma unroll
            for (int off = 32; off; off >>= 1) m = fmaxf(m, __shfl_xor(m, off));
            float e = (tid < 63) ? __expf(sc - m) : 0.f;
            float s = e;
#pragma unroll
            for (int off = 32; off; off >>= 1) s += __shfl_xor(s, off);
            s_attn[tid] = e / s;
        }
        if (tid < 128) s_hc[tid] = 0.f;
        float c = 0.f; // carried by threads 0..127
        __syncthreads();

        for (int t = 0; t < 64; ++t) {
            if (tid < 64) s_wi[tid] = (tid < 63) ? s_attn[tid] * xb[t * 64 + tid + 1] : 0.f;
            __syncthreads();
            float a0 = bias, a1 = 0.f, a2 = 0.f, a3 = 0.f;
#pragma unroll
            for (int n = 0; n < 64; n += 4) {
                float4 v = *(const float4*)&s_wi[n];
                a0 += wih[n]   * v.x; a1 += wih[n+1] * v.y;
                a2 += wih[n+2] * v.z; a3 += wih[n+3] * v.w;
            }
#pragma unroll
            for (int k = 0; k < 128; k += 4) {
                float4 v = *(const float4*)&s_hc[k];
                a0 += whh[k]   * v.x; a1 += whh[k+1] * v.y;
                a2 += whh[k+2] * v.z; a3 += whh[k+3] * v.w;
            }
            const float acc = (a0 + a1) + (a2 + a3);
            const int q = tid >> 7; // 0:i 1:f 2:g 3:o
            s_g[tid] = (q == 2) ? fast_tanh(acc) : fast_sig(acc);
            __syncthreads();
            if (tid < 128) {
                c = s_g[128 + tid] * c + s_g[tid] * s_g[256 + tid];
                float h = s_g[384 + tid] * fast_tanh(c);
                s_hc[tid] = h;
                s_enc[t * 128 + tid] = h;
            }
            __syncthreads();
        }
    }

    // ============ enc_proj epilogue: s_ep[t][f] = enc[t]@W1e[f] + b1[f] ============
    {
        const int f = tid & 127, tq = tid >> 7;
        float w1e[128];
#pragma unroll
        for (int e = 0; e < 128; ++e) w1e[e] = dW1[f * 384 + 256 + e];
        const float b1 = db1[f];
        for (int i = 0; i < 16; ++i) {
            const int trow = tq * 16 + i;
            float a0 = b1, a1 = 0.f, a2 = 0.f, a3 = 0.f;
#pragma unroll
            for (int e = 0; e < 128; e += 4) {
                float4 v = *(const float4*)&s_enc[trow * 128 + e];
                a0 += w1e[e]   * v.x; a1 += w1e[e+1] * v.y;
                a2 += w1e[e+2] * v.z; a3 += w1e[e+3] * v.w;
            }
            s_ep[trow * 128 + f] = (a0 + a1) + (a2 + a3);
        }
    }
    if (tid < 256) s_hc[tid] = 0.f; // reset [h;c] for decoder
    __syncthreads();

    // ================= decoder =================
    {
        // per-thread weights
        float whh[128];                      // dec_Whh row tid
#pragma unroll
        for (int k = 0; k < 128; ++k) whh[k] = dWhh[tid * 128 + k];
        const float bias  = dbih[tid] + dbhh[tid];
        const float wih_s = dWih[tid];       // (512,1)
        const int f4 = tid >> 2, qq = tid & 3, qq2 = (tid & 3) * 2;
        // w1: [W1h|W1c] row f4, quarter qq, chunk order ROTATED by qq*2 so the
        // 4 qq-lanes hit 4 distinct LDS banks in P1 (was a 4-way conflict).
        float w1[64];
#pragma unroll
        for (int j = 0; j < 16; ++j) {
            const int cj = (j + qq2) & 15;
#pragma unroll
            for (int r = 0; r < 4; ++r)
                w1[4*j + r] = dW1[f4 * 384 + qq * 64 + cj * 4 + r];
        }
        // this thread's fixed ep slice, chunk order ROTATED by p for P2
        const int tp = tid >> 3, p = tid & 7;
        float epr[16];
#pragma unroll
        for (int cc = 0; cc < 4; ++cc) {
            const int cj = (cc + p) & 3;
            float4 v = *(const float4*)&s_ep[tid * 16 + cj * 4];
            epr[4*cc] = v.x; epr[4*cc+1] = v.y; epr[4*cc+2] = v.z; epr[4*cc+3] = v.w;
        }
        float c = 0.f; // carried by threads 0..127

        for (int t = 0; t < 64; ++t) {
            // P1: s_hp[f] = [h;c] . [W1h|W1c][f]   (4 lanes per f, rotated chunks)
            {
                float a0 = 0.f, a1 = 0.f, a2 = 0.f, a3 = 0.f;
#pragma unroll
                for (int j = 0; j < 16; ++j) {
                    const int cj = (j + qq2) & 15;
                    float4 v = *(const float4*)&s_hc[qq * 64 + cj * 4];
                    a0 += w1[4*j]   * v.x; a1 += w1[4*j+1] * v.y;
                    a2 += w1[4*j+2] * v.z; a3 += w1[4*j+3] * v.w;
                }
                float a = (a0 + a1) + (a2 + a3);
                a += __shfl_xor(a, 1);
                a += __shfl_xor(a, 2);
                if (qq == 0) s_hp[f4] = a;
            }
            __syncthreads();
            // P2: score[tp] = sum_f W2[f]*tanh(ep[tp][f]+hp[f])  (8 lanes per tp,
            // chunk order rotated by p -> <=2-way LDS aliasing, free)
            {
                float a = 0.f;
#pragma unroll
                for (int cc = 0; cc < 4; ++cc) {
                    const int cj = (cc + p) & 3;
                    float4 hv = *(const float4*)&s_hp [p * 16 + cj * 4];
                    float4 wv = *(const float4*)&s_W2v[p * 16 + cj * 4];
                    const int i0 = cc * 4;
                    a += wv.x * fast_tanh(epr[i0]   + hv.x);
                    a += wv.y * fast_tanh(epr[i0+1] + hv.y);
                    a += wv.z * fast_tanh(epr[i0+2] + hv.z);
                    a += wv.w * fast_tanh(epr[i0+3] + hv.w);
                }
                a += __shfl_xor(a, 1);
                a += __shfl_xor(a, 2);
                a += __shfl_xor(a, 4);
                if (p == 0) s_sc[tp] = a;
            }
            __syncthreads();
            // P3: softmax over 64 scores (wave 0)
            if (tid < 64) {
                float sc = s_sc[tid];
                float m = sc;
#pragma unroll
                for (int off = 32; off; off >>= 1) m = fmaxf(m, __shfl_xor(m, off));
                float e = __expf(sc - m);
                float s = e;
#pragma unroll
                for (int off = 32; off; off >>= 1) s += __shfl_xor(s, off);
                s_sc[tid] = e / s;
            }
            __syncthreads();
            // P4: context partials over t' quarters
            {
                const int e = tid & 127, q2 = tid >> 7;
                float a0 = 0.f, a1 = 0.f;
#pragma unroll
                for (int i = 0; i < 16; i += 2) {
                    a0 += s_sc[q2 * 16 + i]     * s_enc[(q2 * 16 + i)     * 128 + e];
                    a1 += s_sc[q2 * 16 + i + 1] * s_enc[(q2 * 16 + i + 1) * 128 + e];
                }
                s_cp[tid] = a0 + a1;
            }
            __syncthreads();
            // P5: context reduce
            if (tid < 128)
                s_ctx[tid] = s_cp[tid] + s_cp[128 + tid] + s_cp[256 + tid] + s_cp[384 + tid];
            __syncthreads();
            // P6: y_tilde = ctx.fcW[0:128] + y_t*fcW[128] + fcb  (wave 0)
            if (tid < 64) {
                float a = s_ctx[tid] * s_fc[tid] + s_ctx[64 + tid] * s_fc[64 + tid];
#pragma unroll
                for (int off = 32; off; off >>= 1) a += __shfl_xor(a, off);
                if (tid == 0) s_yt = a + xb[t * 64] * s_fc[128] + s_fc[129];
            }
            __syncthreads();
            // P7: gates
            {
                float a0 = bias + s_yt * wih_s, a1 = 0.f, a2 = 0.f, a3 = 0.f;
#pragma unroll
                for (int k = 0; k < 128; k += 4) {
                    float4 v = *(const float4*)&s_hc[k];
                    a0 += whh[k]   * v.x; a1 += whh[k+1] * v.y;
                    a2 += whh[k+2] * v.z; a3 += whh[k+3] * v.w;
                }
                const float acc = (a0 + a1) + (a2 + a3);
                const int q = tid >> 7;
                s_g[tid] = (q == 2) ? fast_tanh(acc) : fast_sig(acc);
            }
            __syncthreads();
            // P8: LSTM state update
            if (tid < 128) {
                c = s_g[128 + tid] * c + s_g[tid] * s_g[256 + tid];
                float h = s_g[384 + tid] * fast_tanh(c);
                s_hc[tid]       = h;
                s_hc[128 + tid] = c;
            }
            __syncthreads();
        }
    }

    // out[b] = [h, context] . fcf_W + fcf_b
    if (tid < 64) {
        float a = s_hc[tid]      * fcfW[tid]
                + s_hc[64 + tid] * fcfW[64 + tid]
                + s_ctx[tid]     * fcfW[128 + tid]
                + s_ctx[64 + tid]* fcfW[192 + tid];
#pragma unroll
        for (int off = 32; off; off >>= 1) a += __shfl_xor(a, off);
        if (tid == 0) out[blockIdx.x] = a + fcfb[0];
    }
}

extern "C" void kernel_launch(void* const* d_in, const int* in_sizes, int n_in,
                              void* d_out, int out_size, void* d_ws, size_t ws_size,
                              hipStream_t stream) {
    const float* x      = (const float*)d_in[0];
    const float* aW     = (const float*)d_in[1];
    const float* ab     = (const float*)d_in[2];
    const float* eWih   = (const float*)d_in[3];
    const float* eWhh   = (const float*)d_in[4];
    const float* ebih   = (const float*)d_in[5];
    const float* ebhh   = (const float*)d_in[6];
    const float* dW1    = (const float*)d_in[7];
    const float* db1    = (const float*)d_in[8];
    const float* W2     = (const float*)d_in[9];
    // d_in[10] = dec_b2: constant added before softmax -> cancels, unused.
    const float* dWih   = (const float*)d_in[11];
    const float* dWhh   = (const float*)d_in[12];
    const float* dbih   = (const float*)d_in[13];
    const float* dbhh   = (const float*)d_in[14];
    const float* fcW    = (const float*)d_in[15];
    const float* fcb    = (const float*)d_in[16];
    const float* fcfW   = (const float*)d_in[17];
    const float* fcfb   = (const float*)d_in[18];
    float* out = (float*)d_out;

    darnn_fused<<<dim3(512), dim3(512), 0, stream>>>(
        x, aW, ab, eWih, eWhh, ebih, ebhh, dW1, db1, W2,
        dWih, dWhh, dbih, dbhh, fcW, fcb, fcfW, fcfb, out);
}

// Round 3
// 1116.406 us; speedup vs baseline: 1.1144x; 1.1144x over previous
//
#include <hip/hip_runtime.h>

// DA-RNN forward, fully fused: one block per batch element (B=512).
// Dims: T=64 steps, 63 input series, H=D=E=128, gates 4H=512 = blockDim.
// Thread j owns row j of the recurrent weight matrices in registers.
// R3: amdgpu_waves_per_eu(1,2) -> 256-VGPR cap (kill scratch spills, which
// were 86MB/launch of WRITE_SIZE at VGPR=128); x staged in LDS (aliases s_ep)
// with attention folded into wih (attn is time-invariant); x-dot pipelined
// into the encoder update phase; decoder ctx-reduce+y_tilde merged onto wave0
// and overlapped with the all-thread whh dot.

__device__ __forceinline__ float fast_rcp(float x) {
    return __builtin_amdgcn_rcpf(x);
}
__device__ __forceinline__ float fast_tanh(float x) {
    // tanh(x) = 1 - 2/(1+e^{2x}); safe at +-inf
    return 1.f - 2.f * fast_rcp(1.f + __expf(2.f * x));
}
__device__ __forceinline__ float fast_sig(float x) {
    return fast_rcp(1.f + __expf(-x));
}

__global__ __attribute__((amdgpu_flat_work_group_size(512, 512),
                          amdgpu_waves_per_eu(1, 2)))
void darnn_fused(
    const float* __restrict__ x,                                    // (512,64,64)
    const float* __restrict__ aW,  const float* __restrict__ ab,    // (320),(1)
    const float* __restrict__ eWih, const float* __restrict__ eWhh, // (512,63),(512,128)
    const float* __restrict__ ebih, const float* __restrict__ ebhh, // (512),(512)
    const float* __restrict__ dW1,  const float* __restrict__ db1,  // (128,384),(128)
    const float* __restrict__ W2,                                   // (128)  [dec_W2 row 0]
    const float* __restrict__ dWih, const float* __restrict__ dWhh, // (512,1),(512,128)
    const float* __restrict__ dbih, const float* __restrict__ dbhh, // (512),(512)
    const float* __restrict__ fcW,  const float* __restrict__ fcb,  // (129),(1)
    const float* __restrict__ fcfW, const float* __restrict__ fcfb, // (256),(1)
    float* __restrict__ out)                                        // (512)
{
    const int b   = blockIdx.x;
    const int tid = threadIdx.x;
    const float* xb = x + b * 4096;   // x[b,t,s] = xb[t*64+s]

    __shared__ float s_enc[64 * 128]; // input_encoded[t][e]   32KB
    __shared__ float s_ep [64 * 128]; // enc_proj[t][f] (+b1)  32KB
    __shared__ float s_attn[64];      // encoder input attention (time-invariant!)
    __shared__ float s_g[512];        // activated gates
    __shared__ float s_hc[256];       // [h(128); c(128)]
    __shared__ float s_hp[128];       // h@W1h.T + c@W1c.T
    __shared__ float s_sc[64];        // dec scores -> attn
    __shared__ float s_cp[512];       // context partials
    __shared__ float s_ctx[128];      // context
    __shared__ float s_W2v[128];
    __shared__ float s_fc[130];       // fc_W(129) + fc_b
    __shared__ float s_y[64];         // y_hist column x[b,t,0]
    __shared__ float s_yt;

    float* const s_x = s_ep;          // (64 t, 64 n) staged xin; dead before
                                      // the epilogue writes s_ep.

    if (tid < 128) s_W2v[tid] = W2[tid];
    if (tid < 130) s_fc[tid] = (tid < 129) ? fcW[tid] : fcb[0];
    if (tid < 64)  s_y[tid] = xb[tid * 64];

    // ================= encoder =================
    {
        // stage xin into LDS: s_x[t*64+n] = x[b,t,n+1], col 63 zero-padded
#pragma unroll
        for (int i = tid; i < 4096; i += 512)
            s_x[i] = ((i & 63) != 63) ? xb[i + 1] : 0.f;
        if (tid < 128) s_hc[tid] = 0.f;
        __syncthreads();

        // wave 0: encoder input attention. score = h@Wh + c@Wc is a per-row
        // SCALAR broadcast over series -> softmax is shift-invariant -> attn is
        // constant over time: attn = softmax_n( sum_t x[b,t,n+1]*Wt[t] + ab ).
        if (tid < 64) {
            float sc = -1e30f;
            if (tid < 63) {
                sc = ab[0];
                for (int t = 0; t < 64; ++t) sc += s_x[t * 64 + tid] * aW[256 + t];
            }
            float m = sc;
#pragma unroll
            for (int off = 32; off; off >>= 1) m = fmaxf(m, __shfl_xor(m, off));
            float e = (tid < 63) ? __expf(sc - m) : 0.f;
            float s = e;
#pragma unroll
            for (int off = 32; off; off >>= 1) s += __shfl_xor(s, off);
            s_attn[tid] = e / s;
        }

        // per-thread weights (global loads overlap wave0's attn work)
        float wih[64];
        float whh[128];
#pragma unroll
        for (int n = 0; n < 63; ++n) wih[n] = eWih[tid * 63 + n];
        wih[63] = 0.f;
#pragma unroll
        for (int k = 0; k < 128; ++k) whh[k] = eWhh[tid * 128 + k];
        const float bias = ebih[tid] + ebhh[tid];
        __syncthreads();

        // fold time-invariant attention into wih
#pragma unroll
        for (int n = 0; n < 64; ++n) wih[n] *= s_attn[n];

        // pipelined x-dot for t=0
        float xa;
        {
            float a0 = 0.f, a1 = 0.f, a2 = 0.f, a3 = 0.f;
#pragma unroll
            for (int n = 0; n < 64; n += 4) {
                float4 v = *(const float4*)&s_x[n];
                a0 += wih[n]   * v.x; a1 += wih[n+1] * v.y;
                a2 += wih[n+2] * v.z; a3 += wih[n+3] * v.w;
            }
            xa = (a0 + a1) + (a2 + a3);
        }
        float c = 0.f; // carried by threads 0..127

        for (int t = 0; t < 64; ++t) {
            // phase C: gates = act( bias + xa + h.whh )
            float a0 = bias + xa, a1 = 0.f, a2 = 0.f, a3 = 0.f;
#pragma unroll
            for (int k = 0; k < 128; k += 4) {
                float4 v = *(const float4*)&s_hc[k];
                a0 += whh[k]   * v.x; a1 += whh[k+1] * v.y;
                a2 += whh[k+2] * v.z; a3 += whh[k+3] * v.w;
            }
            const float acc = (a0 + a1) + (a2 + a3);
            const int q = tid >> 7; // 0:i 1:f 2:g 3:o
            s_g[tid] = (q == 2) ? fast_tanh(acc) : fast_sig(acc);
            __syncthreads();
            // phase B: state update (2 waves) + next-step x-dot (all waves)
            if (tid < 128) {
                c = s_g[128 + tid] * c + s_g[tid] * s_g[256 + tid];
                float h = s_g[384 + tid] * fast_tanh(c);
                s_hc[tid] = h;
                s_enc[t * 128 + tid] = h;
            }
            if (t < 63) {
                float b0 = 0.f, b1 = 0.f, b2 = 0.f, b3 = 0.f;
#pragma unroll
                for (int n = 0; n < 64; n += 4) {
                    float4 v = *(const float4*)&s_x[(t + 1) * 64 + n];
                    b0 += wih[n]   * v.x; b1 += wih[n+1] * v.y;
                    b2 += wih[n+2] * v.z; b3 += wih[n+3] * v.w;
                }
                xa = (b0 + b1) + (b2 + b3);
            }
            __syncthreads();
        }
    }

    // ============ enc_proj epilogue: s_ep[t][f] = enc[t]@W1e[f] + b1[f] ============
    {
        const int f = tid & 127, tq = tid >> 7;
        float w1e[128];
#pragma unroll
        for (int e = 0; e < 128; ++e) w1e[e] = dW1[f * 384 + 256 + e];
        const float b1 = db1[f];
        for (int i = 0; i < 16; ++i) {
            const int trow = tq * 16 + i;
            float a0 = b1, a1 = 0.f, a2 = 0.f, a3 = 0.f;
#pragma unroll
            for (int e = 0; e < 128; e += 4) {
                float4 v = *(const float4*)&s_enc[trow * 128 + e];
                a0 += w1e[e]   * v.x; a1 += w1e[e+1] * v.y;
                a2 += w1e[e+2] * v.z; a3 += w1e[e+3] * v.w;
            }
            s_ep[trow * 128 + f] = (a0 + a1) + (a2 + a3);
        }
    }
    if (tid < 256) s_hc[tid] = 0.f; // reset [h;c] for decoder
    __syncthreads();

    // ================= decoder =================
    {
        // per-thread weights
        float whh[128];                      // dec_Whh row tid
#pragma unroll
        for (int k = 0; k < 128; ++k) whh[k] = dWhh[tid * 128 + k];
        const float bias  = dbih[tid] + dbhh[tid];
        const float wih_s = dWih[tid];       // (512,1)
        const int f4 = tid >> 2, qq = tid & 3, qq2 = (tid & 3) * 2;
        // w1: [W1h|W1c] row f4, quarter qq, chunk order ROTATED by qq*2 so the
        // 4 qq-lanes hit 4 distinct LDS banks in P1.
        float w1[64];
#pragma unroll
        for (int j = 0; j < 16; ++j) {
            const int cj = (j + qq2) & 15;
#pragma unroll
            for (int r = 0; r < 4; ++r)
                w1[4*j + r] = dW1[f4 * 384 + qq * 64 + cj * 4 + r];
        }
        // this thread's fixed ep slice, chunk order ROTATED by p for P2
        const int tp = tid >> 3, p = tid & 7;
        float epr[16];
#pragma unroll
        for (int cc = 0; cc < 4; ++cc) {
            const int cj = (cc + p) & 3;
            float4 v = *(const float4*)&s_ep[tid * 16 + cj * 4];
            epr[4*cc] = v.x; epr[4*cc+1] = v.y; epr[4*cc+2] = v.z; epr[4*cc+3] = v.w;
        }
        float c = 0.f; // carried by threads 0..127

        for (int t = 0; t < 64; ++t) {
            // P1: s_hp[f] = [h;c] . [W1h|W1c][f]   (4 lanes per f, rotated chunks)
            {
                float a0 = 0.f, a1 = 0.f, a2 = 0.f, a3 = 0.f;
#pragma unroll
                for (int j = 0; j < 16; ++j) {
                    const int cj = (j + qq2) & 15;
                    float4 v = *(const float4*)&s_hc[qq * 64 + cj * 4];
                    a0 += w1[4*j]   * v.x; a1 += w1[4*j+1] * v.y;
                    a2 += w1[4*j+2] * v.z; a3 += w1[4*j+3] * v.w;
                }
                float a = (a0 + a1) + (a2 + a3);
                a += __shfl_xor(a, 1);
                a += __shfl_xor(a, 2);
                if (qq == 0) s_hp[f4] = a;
            }
            __syncthreads();
            // P2: score[tp] = sum_f W2[f]*tanh(ep[tp][f]+hp[f])  (8 lanes per tp)
            {
                float a = 0.f;
#pragma unroll
                for (int cc = 0; cc < 4; ++cc) {
                    const int cj = (cc + p) & 3;
                    float4 hv = *(const float4*)&s_hp [p * 16 + cj * 4];
                    float4 wv = *(const float4*)&s_W2v[p * 16 + cj * 4];
                    const int i0 = cc * 4;
                    a += wv.x * fast_tanh(epr[i0]   + hv.x);
                    a += wv.y * fast_tanh(epr[i0+1] + hv.y);
                    a += wv.z * fast_tanh(epr[i0+2] + hv.z);
                    a += wv.w * fast_tanh(epr[i0+3] + hv.w);
                }
                a += __shfl_xor(a, 1);
                a += __shfl_xor(a, 2);
                a += __shfl_xor(a, 4);
                if (p == 0) s_sc[tp] = a;
            }
            __syncthreads();
            // P3: softmax over 64 scores (wave 0)
            if (tid < 64) {
                float sc = s_sc[tid];
                float m = sc;
#pragma unroll
                for (int off = 32; off; off >>= 1) m = fmaxf(m, __shfl_xor(m, off));
                float e = __expf(sc - m);
                float s = e;
#pragma unroll
                for (int off = 32; off; off >>= 1) s += __shfl_xor(s, off);
                s_sc[tid] = e / s;
            }
            __syncthreads();
            // P4: context partials over t' quarters
            {
                const int e = tid & 127, q2 = tid >> 7;
                float a0 = 0.f, a1 = 0.f;
#pragma unroll
                for (int i = 0; i < 16; i += 2) {
                    a0 += s_sc[q2 * 16 + i]     * s_enc[(q2 * 16 + i)     * 128 + e];
                    a1 += s_sc[q2 * 16 + i + 1] * s_enc[(q2 * 16 + i + 1) * 128 + e];
                }
                s_cp[tid] = a0 + a1;
            }
            __syncthreads();
            // P5': wave0 finishes ctx + y_tilde while ALL threads do the whh dot
            if (tid < 64) {
                const float clo = s_cp[tid]      + s_cp[128 + tid]
                                + s_cp[256 + tid] + s_cp[384 + tid];
                const float chi = s_cp[64 + tid]  + s_cp[192 + tid]
                                + s_cp[320 + tid] + s_cp[448 + tid];
                s_ctx[tid]      = clo;
                s_ctx[64 + tid] = chi;
                float a = clo * s_fc[tid] + chi * s_fc[64 + tid];
#pragma unroll
                for (int off = 32; off; off >>= 1) a += __shfl_xor(a, off);
                if (tid == 0) s_yt = a + s_y[t] * s_fc[128] + s_fc[129];
            }
            float a_hh;
            {
                float a0 = bias, a1 = 0.f, a2 = 0.f, a3 = 0.f;
#pragma unroll
                for (int k = 0; k < 128; k += 4) {
                    float4 v = *(const float4*)&s_hc[k];
                    a0 += whh[k]   * v.x; a1 += whh[k+1] * v.y;
                    a2 += whh[k+2] * v.z; a3 += whh[k+3] * v.w;
                }
                a_hh = (a0 + a1) + (a2 + a3);
            }
            __syncthreads();
            // P6: gates
            {
                const float acc = a_hh + s_yt * wih_s;
                const int q = tid >> 7;
                s_g[tid] = (q == 2) ? fast_tanh(acc) : fast_sig(acc);
            }
            __syncthreads();
            // P8: LSTM state update
            if (tid < 128) {
                c = s_g[128 + tid] * c + s_g[tid] * s_g[256 + tid];
                float h = s_g[384 + tid] * fast_tanh(c);
                s_hc[tid]       = h;
                s_hc[128 + tid] = c;
            }
            __syncthreads();
        }
    }

    // out[b] = [h, context] . fcf_W + fcf_b
    if (tid < 64) {
        float a = s_hc[tid]      * fcfW[tid]
                + s_hc[64 + tid] * fcfW[64 + tid]
                + s_ctx[tid]     * fcfW[128 + tid]
                + s_ctx[64 + tid]* fcfW[192 + tid];
#pragma unroll
        for (int off = 32; off; off >>= 1) a += __shfl_xor(a, off);
        if (tid == 0) out[blockIdx.x] = a + fcfb[0];
    }
}

extern "C" void kernel_launch(void* const* d_in, const int* in_sizes, int n_in,
                              void* d_out, int out_size, void* d_ws, size_t ws_size,
                              hipStream_t stream) {
    const float* x      = (const float*)d_in[0];
    const float* aW     = (const float*)d_in[1];
    const float* ab     = (const float*)d_in[2];
    const float* eWih   = (const float*)d_in[3];
    const float* eWhh   = (const float*)d_in[4];
    const float* ebih   = (const float*)d_in[5];
    const float* ebhh   = (const float*)d_in[6];
    const float* dW1    = (const float*)d_in[7];
    const float* db1    = (const float*)d_in[8];
    const float* W2     = (const float*)d_in[9];
    // d_in[10] = dec_b2: constant added before softmax -> cancels, unused.
    const float* dWih   = (const float*)d_in[11];
    const float* dWhh   = (const float*)d_in[12];
    const float* dbih   = (const float*)d_in[13];
    const float* dbhh   = (const float*)d_in[14];
    const float* fcW    = (const float*)d_in[15];
    const float* fcb    = (const float*)d_in[16];
    const float* fcfW   = (const float*)d_in[17];
    const float* fcfb   = (const float*)d_in[18];
    float* out = (float*)d_out;

    darnn_fused<<<dim3(512), dim3(512), 0, stream>>>(
        x, aW, ab, eWih, eWhh, ebih, ebhh, dW1, db1, W2,
        dWih, dWhh, dbih, dbhh, fcW, fcb, fcfW, fcfb, out);
}